// Round 7
// baseline (174.923 us; speedup 1.0000x reference)
//
#include <hip/hip_runtime.h>

#define Bdim 16
#define Sdim 16
#define Edim 256
#define Hdim 512
#define Vdim 16000
#define THR1f 0.8f
#define THR2f 1.0f

typedef unsigned int   u32;
typedef unsigned short u16;
typedef __attribute__((ext_vector_type(8))) short bf16x8;
typedef __attribute__((ext_vector_type(4))) float f32x4;
typedef __attribute__((ext_vector_type(4))) u32   u32x4;

__device__ __forceinline__ u16 f2bf(float f) {          // RNE fp32->bf16
  u32 u = __float_as_uint(f);
  return (u16)((u + 0x7FFFu + ((u >> 16) & 1u)) >> 16);
}
__device__ __forceinline__ u32 pack2(float a, float b) {
  return (u32)f2bf(a) | ((u32)f2bf(b) << 16);
}

// ---------------------------------------------------------------------------
// K1: prep = cur1 GEMM (fp32, exact) + m1 Leaky recurrence (fp32, exact).
// Grid (8 h-tiles, 4 b-tiles) x 256 thr. Block owns 4 batches x ALL 16 tokens
// x 64 h's -> can run the full m1 recurrence in-block.
// Emits Ab3 in MFMA-fragment-contiguous layout:
//   value(A-row r = 32t+2b+c, col h) at u16 index
//   ((S*32+R)*64 + l)*8 + j,  S=h>>5, R=r>>4, l=((h>>3)&3)*16+(r&15), j=h&7
// so GEMM frag (R,S) lane l reads 16 contiguous bytes at ((S*32+R)*64+l)*16.
// ---------------------------------------------------------------------------
__global__ __launch_bounds__(256) void snn_prep(
    const int* __restrict__ x, const float* __restrict__ embed_w,
    const float* __restrict__ fc1_w, const float* __restrict__ fc1_b,
    const float* __restrict__ beta1p, const int* __restrict__ tsp,
    u16* __restrict__ Ab3, float* __restrict__ mem1)
{
  __shared__ __align__(16) float As[64][68];
  __shared__ __align__(16) float Ws[64][68];
  __shared__ float cbuf[64][68];
  __shared__ int sidx[64];
  const int tid = threadIdx.x;
  const int n0  = blockIdx.x * 64;       // h tile
  const int bi0 = blockIdx.y * 4;        // b tile
  const int tx = tid & 15, ty = tid >> 4;

  // row rr = t*4 + bb  ->  token t = rr>>2, batch bi0 + (rr&3)
  if (tid < 64) sidx[tid] = x[(bi0 + (tid & 3)) * Sdim + (tid >> 2)];

  float acc[4][4] = {{0.f}};
  for (int k0 = 0; k0 < Edim; k0 += 64) {
    __syncthreads();                     // also covers sidx on iter 0
#pragma unroll
    for (int i = 0; i < 16; ++i) {
      const int k = tid + i * 256;
      const int rr = k >> 6, j = k & 63;
      As[j][rr] = embed_w[(size_t)sidx[rr] * Edim + k0 + j];
      Ws[j][rr] = fc1_w[(size_t)(n0 + rr) * Edim + k0 + j];
    }
    __syncthreads();
#pragma unroll
    for (int j = 0; j < 64; ++j) {
      const float4 av = *(const float4*)&As[j][ty * 4];
      const float4 wv = *(const float4*)&Ws[j][tx * 4];
      const float a[4] = {av.x, av.y, av.z, av.w};
      const float w[4] = {wv.x, wv.y, wv.z, wv.w};
#pragma unroll
      for (int i = 0; i < 4; ++i)
#pragma unroll
        for (int jj = 0; jj < 4; ++jj)
          acc[i][jj] = fmaf(a[i], w[jj], acc[i][jj]);
    }
  }
#pragma unroll
  for (int i = 0; i < 4; ++i)
#pragma unroll
    for (int jj = 0; jj < 4; ++jj)
      cbuf[ty * 4 + i][tx * 4 + jj] = acc[i][jj] + fc1_b[n0 + tx * 4 + jj];
  __syncthreads();

  // ---- phase 2: m1 recurrence, thread = (bb, hl) ----
  const int bb = tid >> 6, hl = tid & 63;
  const int b  = bi0 + bb;
  const int hg = n0 + hl;
  const float b1 = fminf(fmaxf(beta1p[0], 0.f), 1.f);
  const int T = tsp[0];

  double w9T = 1.0, w8T = 1.0;
  for (int i = 0; i < T; ++i) { w9T *= 0.9; w8T *= 0.8; }

  const int S = hg >> 5, q = (hg >> 3) & 3, jc = hg & 7;

  float m1 = 0.f;
  for (int t = 0; t < Sdim; ++t) {
    const float cur = cbuf[t * 4 + bb][hl];
    double p9 = w9T, p8 = w8T;             // 0.9^{T-u}, 0.8^{T-u}
    float cs = 0.f, cm = 0.f;
    for (int u = 0; u < T; ++u) {
      const float reset = (m1 > THR1f) ? THR1f : 0.f;
      m1 = b1 * m1 + cur - reset;
      if (m1 > THR1f) {
        cs += (float)(p9 * (10.0 / 9.0));  // 0.9^{T-1-u}
        cm += (float)(10.0 * (p9 - p8));   // wm_u
      }
      p9 *= (10.0 / 9.0);
      p8 *= 1.25;
    }
    int rb = 2 * b;                        // c = 0 (cs)
    int R  = 2 * t + (rb >> 4);
    int l  = q * 16 + (rb & 15);
    Ab3[((size_t)(S * 32 + R) * 64 + l) * 8 + jc] = f2bf(cs);
    rb = 2 * b + 1;                        // c = 1 (cm)
    R  = 2 * t + (rb >> 4);
    l  = q * 16 + (rb & 15);
    Ab3[((size_t)(S * 32 + R) * 64 + l) * 8 + jc] = f2bf(cm);
  }
  mem1[b * Hdim + hg] = m1;
}

// ---------------------------------------------------------------------------
// K2: fused GEMM + Synaptic recurrence + spikes.  v3: NO LDS, NO barriers.
// 250 blocks x 4 waves; wave owns cols v0+wn*16+(lane&15), ALL 512 rows.
// A-frags: contiguous 1KB loads from Ab3 (L2-resident). B-frags: W fp32
// read directly (HBM, once) + in-register bf16 pack, next-S prefetched.
// acc[R], R=0..31: rows 16R + (lane>>4)*4 + e.  Epilogue = R5-v1 verified:
// b = hi*8 + 2g + j (g=lane>>4), gs=acc[2t+hi][2j], gm=acc[2t+hi][2j+1].
// ---------------------------------------------------------------------------
__global__ __launch_bounds__(256, 1) void snn_fused(
    const u16* __restrict__ Ab3, const float* __restrict__ W,
    const float* __restrict__ fc2_b, const int* __restrict__ tsp,
    float* __restrict__ out, float* __restrict__ syn2, float* __restrict__ mem2)
{
  const int tid  = threadIdx.x;
  const int lane = tid & 63;
  const int wn   = tid >> 6;
  const int v0   = blockIdx.x * 64;
  const int v    = v0 + wn * 16 + (lane & 15);

  f32x4 acc[32];
#pragma unroll
  for (int R = 0; R < 32; ++R)
#pragma unroll
    for (int e = 0; e < 4; ++e) acc[R][e] = 0.f;

  const float* wrow = W + (size_t)v * Hdim + ((lane >> 4) * 8);
  float4 wa = *(const float4*)(wrow);
  float4 wb = *(const float4*)(wrow + 4);

  for (int S = 0; S < 16; ++S) {
    const int Sn = (S + 1) & 15;               // wraps; S=15 prefetch unused
    const float4 na = *(const float4*)(wrow + Sn * 32);
    const float4 nb = *(const float4*)(wrow + Sn * 32 + 4);
    u32x4 bw;
    bw.x = pack2(wa.x, wa.y); bw.y = pack2(wa.z, wa.w);
    bw.z = pack2(wb.x, wb.y); bw.w = pack2(wb.z, wb.w);
    const bf16x8 bfr = __builtin_bit_cast(bf16x8, bw);
    const char* abase = (const char*)Ab3 + (size_t)S * 32768 + lane * 16;
#pragma unroll
    for (int R = 0; R < 32; ++R) {
      const bf16x8 af = *(const bf16x8*)(abase + R * 1024);
      acc[R] = __builtin_amdgcn_mfma_f32_16x16x32_bf16(af, bfr, acc[R],
                                                       0, 0, 0);
    }
    wa = na; wb = nb;
  }

  // ---- in-register Synaptic recurrence + spike emission ----
  const int T = tsp[0];
  double p9 = 1.0, p8 = 1.0;
  for (int i = 0; i < T; ++i) { p9 *= 0.9; p8 *= 0.8; }
  const float Ps  = (float)p9;                       // 0.9^T
  const float Pm  = (float)p8;                       // 0.8^T
  const float Pms = (float)(0.9 * 10.0 * (p9 - p8)); // s2-coeff into m2
  const float Sws = (float)(10.0 * (1.0 - p9));
  const float Swm = (float)(10.0 * (9.0 * (1.0 - p9) - 4.0 * (1.0 - p8)));

  const int g = lane >> 4;
  const float bbv = fc2_b[v];
  const float bbs = bbv * Sws;
  const float bbm = bbv * Swm;

#pragma unroll
  for (int hi = 0; hi < 2; ++hi) {
#pragma unroll
    for (int j = 0; j < 2; ++j) {
      const int b = hi * 8 + 2 * g + j;
      float s2 = 0.f, m2 = 0.f;
#pragma unroll
      for (int t = 0; t < Sdim; ++t) {
        const float gs = acc[2 * t + hi][2 * j];
        const float gm = acc[2 * t + hi][2 * j + 1];
        const float m2n = Pm * m2 + Pms * s2 + gm + bbm;
        s2 = Ps * s2 + gs + bbs;
        m2 = m2n;
        out[((size_t)b * Sdim + t) * Vdim + v] = (m2n > THR2f) ? 1.f : 0.f;
      }
      syn2[(size_t)b * Vdim + v] = s2;
      mem2[(size_t)b * Vdim + v] = m2;
    }
  }
}

// ---------------------------------------------------------------------------
extern "C" void kernel_launch(void* const* d_in, const int* in_sizes, int n_in,
                              void* d_out, int out_size, void* d_ws, size_t ws_size,
                              hipStream_t stream) {
  const int*   x       = (const int*)d_in[0];
  const float* embed_w = (const float*)d_in[1];
  const float* fc1_w   = (const float*)d_in[2];
  const float* fc1_b   = (const float*)d_in[3];
  const float* fc2_w   = (const float*)d_in[4];
  const float* fc2_b   = (const float*)d_in[5];
  const float* beta1   = (const float*)d_in[6];
  const int*   tsteps  = (const int*)d_in[7];

  float* out  = (float*)d_out;                          // [16][16][16000]
  float* mem1 = out + (size_t)Bdim * Sdim * Vdim;       // [16][512]
  float* syn2 = mem1 + (size_t)Bdim * Hdim;             // [16][16000]
  float* mem2 = syn2 + (size_t)Bdim * Vdim;             // [16][16000]

  u16* Ab3 = (u16*)d_ws;                                // 512 KB

  snn_prep<<<dim3(8, 4), 256, 0, stream>>>(x, embed_w, fc1_w, fc1_b,
                                           beta1, tsteps, Ab3, mem1);
  snn_fused<<<Vdim / 64, 256, 0, stream>>>(Ab3, fc2_w, fc2_b, tsteps,
                                           out, syn2, mem2);
}

// Round 8
// 155.163 us; speedup vs baseline: 1.1273x; 1.1273x over previous
//
#include <hip/hip_runtime.h>

#define Bdim 16
#define Sdim 16
#define Edim 256
#define Hdim 512
#define Vdim 16000
#define THR1f 0.8f
#define THR2f 1.0f

typedef unsigned int   u32;
typedef unsigned short u16;
typedef __attribute__((ext_vector_type(8))) short bf16x8;
typedef __attribute__((ext_vector_type(4))) float f32x4;
typedef __attribute__((ext_vector_type(4))) u32   u32x4;

__device__ __forceinline__ u16 f2bf(float f) {          // RNE fp32->bf16
  u32 u = __float_as_uint(f);
  return (u16)((u + 0x7FFFu + ((u >> 16) & 1u)) >> 16);
}
__device__ __forceinline__ u32 pack2(float a, float b) {
  return (u32)f2bf(a) | ((u32)f2bf(b) << 16);
}

// ---------------------------------------------------------------------------
// K1: prep = cur1 GEMM (fp32, exact) + m1 Leaky recurrence (fp32, exact).
// UNCHANGED from round 7 (verified). Emits Ab3 fragment-contiguous:
//   value(A-row r=32t+2b+c, col h) at ((S*32+R)*64+l)*8+j,
//   S=h>>5, R=r>>4, l=((h>>3)&3)*16+(r&15), j=h&7.
// ---------------------------------------------------------------------------
__global__ __launch_bounds__(256) void snn_prep(
    const int* __restrict__ x, const float* __restrict__ embed_w,
    const float* __restrict__ fc1_w, const float* __restrict__ fc1_b,
    const float* __restrict__ beta1p, const int* __restrict__ tsp,
    u16* __restrict__ Ab3, float* __restrict__ mem1)
{
  __shared__ __align__(16) float As[64][68];
  __shared__ __align__(16) float Ws[64][68];
  __shared__ float cbuf[64][68];
  __shared__ int sidx[64];
  const int tid = threadIdx.x;
  const int n0  = blockIdx.x * 64;       // h tile
  const int bi0 = blockIdx.y * 4;        // b tile
  const int tx = tid & 15, ty = tid >> 4;

  if (tid < 64) sidx[tid] = x[(bi0 + (tid & 3)) * Sdim + (tid >> 2)];

  float acc[4][4] = {{0.f}};
  for (int k0 = 0; k0 < Edim; k0 += 64) {
    __syncthreads();                     // also covers sidx on iter 0
#pragma unroll
    for (int i = 0; i < 16; ++i) {
      const int k = tid + i * 256;
      const int rr = k >> 6, j = k & 63;
      As[j][rr] = embed_w[(size_t)sidx[rr] * Edim + k0 + j];
      Ws[j][rr] = fc1_w[(size_t)(n0 + rr) * Edim + k0 + j];
    }
    __syncthreads();
#pragma unroll
    for (int j = 0; j < 64; ++j) {
      const float4 av = *(const float4*)&As[j][ty * 4];
      const float4 wv = *(const float4*)&Ws[j][tx * 4];
      const float a[4] = {av.x, av.y, av.z, av.w};
      const float w[4] = {wv.x, wv.y, wv.z, wv.w};
#pragma unroll
      for (int i = 0; i < 4; ++i)
#pragma unroll
        for (int jj = 0; jj < 4; ++jj)
          acc[i][jj] = fmaf(a[i], w[jj], acc[i][jj]);
    }
  }
#pragma unroll
  for (int i = 0; i < 4; ++i)
#pragma unroll
    for (int jj = 0; jj < 4; ++jj)
      cbuf[ty * 4 + i][tx * 4 + jj] = acc[i][jj] + fc1_b[n0 + tx * 4 + jj];
  __syncthreads();

  const int bb = tid >> 6, hl = tid & 63;
  const int b  = bi0 + bb;
  const int hg = n0 + hl;
  const float b1 = fminf(fmaxf(beta1p[0], 0.f), 1.f);
  const int T = tsp[0];

  double w9T = 1.0, w8T = 1.0;
  for (int i = 0; i < T; ++i) { w9T *= 0.9; w8T *= 0.8; }

  const int S = hg >> 5, q = (hg >> 3) & 3, jc = hg & 7;

  float m1 = 0.f;
  for (int t = 0; t < Sdim; ++t) {
    const float cur = cbuf[t * 4 + bb][hl];
    double p9 = w9T, p8 = w8T;
    float cs = 0.f, cm = 0.f;
    for (int u = 0; u < T; ++u) {
      const float reset = (m1 > THR1f) ? THR1f : 0.f;
      m1 = b1 * m1 + cur - reset;
      if (m1 > THR1f) {
        cs += (float)(p9 * (10.0 / 9.0));
        cm += (float)(10.0 * (p9 - p8));
      }
      p9 *= (10.0 / 9.0);
      p8 *= 1.25;
    }
    int rb = 2 * b;
    int R  = 2 * t + (rb >> 4);
    int l  = q * 16 + (rb & 15);
    Ab3[((size_t)(S * 32 + R) * 64 + l) * 8 + jc] = f2bf(cs);
    rb = 2 * b + 1;
    R  = 2 * t + (rb >> 4);
    l  = q * 16 + (rb & 15);
    Ab3[((size_t)(S * 32 + R) * 64 + l) * 8 + jc] = f2bf(cm);
  }
  mem1[b * Hdim + hg] = m1;
}

// ---------------------------------------------------------------------------
// K2: fused GEMM + Synaptic recurrence + spikes.  v4: K-split for TLP.
// 1000 blocks x 2 waves. Wave w: cols v0..v0+15 (v0=blockIdx*16), ALL 512
// rows, K-half w (S = 8w..8w+7). acc[32] f32x4. A-loads software-pipelined
// in groups of 8. Cross-wave reduce through 32KB LDS, then both waves run
// the per-b (s2,m2) recurrence reading fragments from LDS:
//   value(row r, col) = red[r>>4][((r&15)>>2)*16+col][r&3]
// (identical to v3's verified b=hi*8+2g+j mapping).
// ---------------------------------------------------------------------------
__global__ __launch_bounds__(128, 2) void snn_fused(
    const u16* __restrict__ Ab3, const float* __restrict__ W,
    const float* __restrict__ fc2_b, const int* __restrict__ tsp,
    float* __restrict__ out, float* __restrict__ syn2, float* __restrict__ mem2)
{
  __shared__ __align__(16) float red[32][64][4];   // 32 KB
  const int tid  = threadIdx.x;          // 0..127
  const int lane = tid & 63;
  const int w    = tid >> 6;             // wave 0/1 = K-half
  const int v0   = blockIdx.x * 16;
  const int col  = lane & 15;
  const int grp  = lane >> 4;
  const int v    = v0 + col;

  f32x4 acc[32];
#pragma unroll
  for (int R = 0; R < 32; ++R)
#pragma unroll
    for (int e = 0; e < 4; ++e) acc[R][e] = 0.f;

  // W row for this lane's col; lane-group grp covers k-bytes grp*8..grp*8+7
  const float* wrow = W + (size_t)v * Hdim + grp * 8;
  float4 wa = *(const float4*)(wrow + (8 * w) * 32);
  float4 wb = *(const float4*)(wrow + (8 * w) * 32 + 4);

  for (int s = 0; s < 8; ++s) {
    const int S  = 8 * w + s;
    const int sn = (s < 7) ? s + 1 : 7;          // clamp (last reloads self)
    const float4 na = *(const float4*)(wrow + (8 * w + sn) * 32);
    const float4 nb = *(const float4*)(wrow + (8 * w + sn) * 32 + 4);

    u32x4 bw;
    bw.x = pack2(wa.x, wa.y); bw.y = pack2(wa.z, wa.w);
    bw.z = pack2(wb.x, wb.y); bw.w = pack2(wb.z, wb.w);
    const bf16x8 bfr = __builtin_bit_cast(bf16x8, bw);

    const char* abase = (const char*)Ab3 + (size_t)S * 32768 + lane * 16;
    bf16x8 af[8], ag[8];
#pragma unroll
    for (int i = 0; i < 8; ++i)
      af[i] = *(const bf16x8*)(abase + i * 1024);
#pragma unroll
    for (int gof = 0; gof < 4; ++gof) {
      bf16x8* curb = (gof & 1) ? ag : af;
      bf16x8* nxtb = (gof & 1) ? af : ag;
      if (gof < 3) {
#pragma unroll
        for (int i = 0; i < 8; ++i)
          nxtb[i] = *(const bf16x8*)(abase + ((gof + 1) * 8 + i) * 1024);
      }
#pragma unroll
      for (int i = 0; i < 8; ++i)
        acc[gof * 8 + i] = __builtin_amdgcn_mfma_f32_16x16x32_bf16(
            curb[i], bfr, acc[gof * 8 + i], 0, 0, 0);
    }
    wa = na; wb = nb;
  }

  // ---- cross-wave K-reduction through LDS ----
  if (w == 1) {
#pragma unroll
    for (int R = 0; R < 32; ++R)
      *(f32x4*)&red[R][lane][0] = acc[R];
  }
  __syncthreads();
  if (w == 0) {
#pragma unroll
    for (int R = 0; R < 32; ++R)
      acc[R] += *(const f32x4*)&red[R][lane][0];
  }
  __syncthreads();
  if (w == 0) {
#pragma unroll
    for (int R = 0; R < 32; ++R)
      *(f32x4*)&red[R][lane][0] = acc[R];
  }
  __syncthreads();

  // ---- epilogue: per-(b,v) Synaptic recurrence + spikes (both waves) ----
  const int T = tsp[0];
  double p9 = 1.0, p8 = 1.0;
  for (int i = 0; i < T; ++i) { p9 *= 0.9; p8 *= 0.8; }
  const float Ps  = (float)p9;                       // 0.9^T
  const float Pm  = (float)p8;                       // 0.8^T
  const float Pms = (float)(0.9 * 10.0 * (p9 - p8)); // s2-coeff into m2
  const float Sws = (float)(10.0 * (1.0 - p9));
  const float Swm = (float)(10.0 * (9.0 * (1.0 - p9) - 4.0 * (1.0 - p8)));

  const float bbv = fc2_b[v];
  const float bbs = bbv * Sws;
  const float bbm = bbv * Swm;

#pragma unroll
  for (int jj = 0; jj < 2; ++jj) {
    const int b = w * 8 + grp * 2 + jj;
    float s2 = 0.f, m2 = 0.f;
#pragma unroll
    for (int t = 0; t < Sdim; ++t) {
      const int rs = 32 * t + 2 * b;
      const float gs = red[rs >> 4][((rs & 15) >> 2) * 16 + col][rs & 3];
      const int rm = rs + 1;
      const float gm = red[rm >> 4][((rm & 15) >> 2) * 16 + col][rm & 3];
      const float m2n = Pm * m2 + Pms * s2 + gm + bbm;
      s2 = Ps * s2 + gs + bbs;
      m2 = m2n;
      out[((size_t)b * Sdim + t) * Vdim + v] = (m2n > THR2f) ? 1.f : 0.f;
    }
    syn2[(size_t)b * Vdim + v] = s2;
    mem2[(size_t)b * Vdim + v] = m2;
  }
}

// ---------------------------------------------------------------------------
extern "C" void kernel_launch(void* const* d_in, const int* in_sizes, int n_in,
                              void* d_out, int out_size, void* d_ws, size_t ws_size,
                              hipStream_t stream) {
  const int*   x       = (const int*)d_in[0];
  const float* embed_w = (const float*)d_in[1];
  const float* fc1_w   = (const float*)d_in[2];
  const float* fc1_b   = (const float*)d_in[3];
  const float* fc2_w   = (const float*)d_in[4];
  const float* fc2_b   = (const float*)d_in[5];
  const float* beta1   = (const float*)d_in[6];
  const int*   tsteps  = (const int*)d_in[7];

  float* out  = (float*)d_out;                          // [16][16][16000]
  float* mem1 = out + (size_t)Bdim * Sdim * Vdim;       // [16][512]
  float* syn2 = mem1 + (size_t)Bdim * Hdim;             // [16][16000]
  float* mem2 = syn2 + (size_t)Bdim * Vdim;             // [16][16000]

  u16* Ab3 = (u16*)d_ws;                                // 512 KB

  snn_prep<<<dim3(8, 4), 256, 0, stream>>>(x, embed_w, fc1_w, fc1_b,
                                           beta1, tsteps, Ab3, mem1);
  snn_fused<<<Vdim / 16, 128, 0, stream>>>(Ab3, fc2_w, fc2_b, tsteps,
                                           out, syn2, mem2);
}